// Round 6
// baseline (386.576 us; speedup 1.0000x reference)
//
#include <hip/hip_runtime.h>

#define NNODES 262144          // N = 2^18
#define HWPIX  1048576         // H*W = 2^20
#define BC     12              // B*C

typedef _Float16 half4 __attribute__((ext_vector_type(4)));
typedef float    f32x4 __attribute__((ext_vector_type(4)));
typedef int      i32x4 __attribute__((ext_vector_type(4)));

__device__ __forceinline__ float sigm(float x) {
    return 1.0f / (1.0f + __expf(-x));
}

// bijective XCD swizzle (requires gridDim.x % 8 == 0, true for all our grids)
__device__ __forceinline__ int xcd_swizzle(int orig, int nwg) {
    int q = nwg >> 3;
    return (orig & 7) * q + (orig >> 3);
}

// Kernel 1: contrib_g = sigmoid(attrs . W_g + b_g) * residue, packed as
// f32x4 {c0,c1,c2,as_float(parent)} -> one 16B gather per chain hop.
// Streaming inputs are read-once -> nontemporal (keep L2 for walk targets).
__global__ __launch_bounds__(256) void k_contrib(
    const float* __restrict__ attrs,   // (BC, N, 3)
    const float* __restrict__ residue, // (BC, N)
    const int*   __restrict__ parent,  // (BC, N)
    const float* __restrict__ W0, const float* __restrict__ W1,
    const float* __restrict__ W2, const float* __restrict__ b0,
    const float* __restrict__ b1, const float* __restrict__ b2,
    f32x4* __restrict__ contrib)       // (BC*N)
{
    const float w0 = W0[0], w10 = W1[0], w11 = W1[1], w2 = W2[0];
    const float c0 = b0[0], c1 = b1[0], c2 = b2[0];

    int t = blockIdx.x * blockDim.x + threadIdx.x;   // quad-node index
    const f32x4* a4 = (const f32x4*)attrs + (size_t)t * 3;
    f32x4 A  = __builtin_nontemporal_load(a4);
    f32x4 Bv = __builtin_nontemporal_load(a4 + 1);
    f32x4 Cv = __builtin_nontemporal_load(a4 + 2);
    f32x4 r  = __builtin_nontemporal_load((const f32x4*)residue + t);
    i32x4 par = __builtin_nontemporal_load((const i32x4*)parent + t);

    f32x4 o0, o1, o2, o3;
    o0.x = r.x * sigm(A.x * w0 + c0);
    o0.y = r.x * sigm(A.y * w10 + A.z * w11 + c1);
    o0.z = r.x * sigm(A.y * w2 + c2);
    o0.w = __int_as_float(par.x);
    o1.x = r.y * sigm(A.w * w0 + c0);
    o1.y = r.y * sigm(Bv.x * w10 + Bv.y * w11 + c1);
    o1.z = r.y * sigm(Bv.x * w2 + c2);
    o1.w = __int_as_float(par.y);
    o2.x = r.z * sigm(Bv.z * w0 + c0);
    o2.y = r.z * sigm(Bv.w * w10 + Cv.x * w11 + c1);
    o2.z = r.z * sigm(Bv.w * w2 + c2);
    o2.w = __int_as_float(par.z);
    o3.x = r.w * sigm(Cv.y * w0 + c0);
    o3.y = r.w * sigm(Cv.z * w10 + Cv.w * w11 + c1);
    o3.z = r.w * sigm(Cv.z * w2 + c2);
    o3.w = __int_as_float(par.w);

    f32x4* dst = contrib + (size_t)t * 4;
    dst[0] = o0; dst[1] = o1; dst[2] = o2; dst[3] = o3;
}

// Kernel 2 (x4 geometric chunks): f[i] = contrib[i] + f[parent-chain].
// CH independent chains per thread -> CH outstanding dependent gathers.
template<int CH, bool BASE>
__global__ __launch_bounds__(256) void k_scan(
    const f32x4* __restrict__ contrib,
    half4* __restrict__ ftab,          // fp16 x3 (+pad), 8B/node
    int lo, int cnt)                   // nodes [lo, lo+cnt) per tree
{
    int w = xcd_swizzle(blockIdx.x, gridDim.x);
    const int sub = cnt / CH;          // chains per k-slot per tree
    const int bpt = sub >> 8;          // blocks per tree
    int bc = w / bpt;
    int i0 = lo + (w % bpt) * 256 + threadIdx.x;
    const f32x4* C = contrib + ((size_t)bc << 18);
    half4* F = ftab + ((size_t)bc << 18);

    int   j[CH];
    float ax[CH], ay[CH], az[CH];
    #pragma unroll
    for (int k = 0; k < CH; ++k) {
        f32x4 e = C[i0 + k * sub];
        ax[k] = e.x; ay[k] = e.y; az[k] = e.z;
        j[k] = __float_as_int(e.w);
    }

    bool any = false;
    #pragma unroll
    for (int k = 0; k < CH; ++k)
        any |= BASE ? (j[k] != NNODES) : (j[k] >= lo);

    while (any) {
        f32x4 e[CH];
        #pragma unroll
        for (int k = 0; k < CH; ++k) {
            bool act = BASE ? (j[k] != NNODES) : (j[k] >= lo);
            e[k] = C[act ? j[k] : 0];
        }
        any = false;
        #pragma unroll
        for (int k = 0; k < CH; ++k) {
            bool act = BASE ? (j[k] != NNODES) : (j[k] >= lo);
            if (act) {
                ax[k] += e[k].x; ay[k] += e[k].y; az[k] += e[k].z;
                j[k] = __float_as_int(e[k].w);
            }
            any |= BASE ? (j[k] != NNODES) : (j[k] >= lo);
        }
    }

    if (BASE) {
        #pragma unroll
        for (int k = 0; k < CH; ++k) {
            half4 h = {(_Float16)ax[k], (_Float16)ay[k], (_Float16)az[k], (_Float16)0.f};
            F[i0 + k * sub] = h;
        }
    } else {
        half4 fp[CH];
        #pragma unroll
        for (int k = 0; k < CH; ++k) fp[k] = F[j[k]];   // finalized ancestors
        #pragma unroll
        for (int k = 0; k < CH; ++k) {
            float fx = ax[k] + (float)fp[k].x;
            float fy = ay[k] + (float)fp[k].y;
            float fz = az[k] + (float)fp[k].z;
            half4 h = {(_Float16)fx, (_Float16)fy, (_Float16)fz, (_Float16)0.f};
            F[i0 + k * sub] = h;
        }
    }
}

// Kernel 3: pixel gather, 16 px/thread (16 outstanding 8B gathers/lane),
// XCD-swizzled (f-table ~3MB/XCD, L2-resident). pixel_node reads and the
// 147MiB output stream are nontemporal so they don't evict the f-table.
__global__ __launch_bounds__(256) void k_gather(
    const half4* __restrict__ f,           // (BC*N)
    const int*   __restrict__ pixel_node,  // (BC, HW)
    float* __restrict__ out)               // (BC, 3, HW)
{
    int w = xcd_swizzle(blockIdx.x, gridDim.x);
    size_t gp = (size_t)w * 4096 + (size_t)threadIdx.x * 16;
    int bc = (int)(gp >> 20);              // HWPIX = 2^20
    int p  = (int)(gp & (HWPIX - 1));
    const i32x4* pn4 = (const i32x4*)(pixel_node + gp);
    i32x4 pa = __builtin_nontemporal_load(pn4);
    i32x4 pb = __builtin_nontemporal_load(pn4 + 1);
    i32x4 pc = __builtin_nontemporal_load(pn4 + 2);
    i32x4 pd = __builtin_nontemporal_load(pn4 + 3);
    const half4* fb = f + ((size_t)bc << 18);
    half4 f0 = fb[pa.x], f1 = fb[pa.y], f2  = fb[pa.z], f3  = fb[pa.w];
    half4 f4 = fb[pb.x], f5 = fb[pb.y], f6  = fb[pb.z], f7  = fb[pb.w];
    half4 f8 = fb[pc.x], f9 = fb[pc.y], f10 = fb[pc.z], f11 = fb[pc.w];
    half4 fc = fb[pd.x], fd = fb[pd.y], fe  = fb[pd.z], ff  = fb[pd.w];
    float* o = out + (size_t)bc * 3 * HWPIX + p;

    f32x4 s0 = {f0.x, f1.x, f2.x, f3.x};
    f32x4 s1 = {f4.x, f5.x, f6.x, f7.x};
    f32x4 s2 = {f8.x, f9.x, f10.x, f11.x};
    f32x4 s3 = {fc.x, fd.x, fe.x, ff.x};
    __builtin_nontemporal_store(s0, (f32x4*)(o));
    __builtin_nontemporal_store(s1, (f32x4*)(o + 4));
    __builtin_nontemporal_store(s2, (f32x4*)(o + 8));
    __builtin_nontemporal_store(s3, (f32x4*)(o + 12));

    o += HWPIX;
    f32x4 t0 = {f0.y, f1.y, f2.y, f3.y};
    f32x4 t1 = {f4.y, f5.y, f6.y, f7.y};
    f32x4 t2 = {f8.y, f9.y, f10.y, f11.y};
    f32x4 t3 = {fc.y, fd.y, fe.y, ff.y};
    __builtin_nontemporal_store(t0, (f32x4*)(o));
    __builtin_nontemporal_store(t1, (f32x4*)(o + 4));
    __builtin_nontemporal_store(t2, (f32x4*)(o + 8));
    __builtin_nontemporal_store(t3, (f32x4*)(o + 12));

    o += HWPIX;
    f32x4 u0 = {f0.z, f1.z, f2.z, f3.z};
    f32x4 u1 = {f4.z, f5.z, f6.z, f7.z};
    f32x4 u2 = {f8.z, f9.z, f10.z, f11.z};
    f32x4 u3 = {fc.z, fd.z, fe.z, ff.z};
    __builtin_nontemporal_store(u0, (f32x4*)(o));
    __builtin_nontemporal_store(u1, (f32x4*)(o + 4));
    __builtin_nontemporal_store(u2, (f32x4*)(o + 8));
    __builtin_nontemporal_store(u3, (f32x4*)(o + 12));
}

extern "C" void kernel_launch(void* const* d_in, const int* in_sizes, int n_in,
                              void* d_out, int out_size, void* d_ws, size_t ws_size,
                              hipStream_t stream) {
    const float* attrs      = (const float*)d_in[0];
    const float* residue    = (const float*)d_in[1];
    const float* W0         = (const float*)d_in[2];
    const float* W1         = (const float*)d_in[3];
    const float* W2         = (const float*)d_in[4];
    const float* b0         = (const float*)d_in[5];
    const float* b1         = (const float*)d_in[6];
    const float* b2         = (const float*)d_in[7];
    const int*   parent     = (const int*)d_in[8];
    const int*   pixel_node = (const int*)d_in[9];
    float* out = (float*)d_out;

    const size_t total_nodes = (size_t)BC * NNODES;       // 3,145,728
    f32x4* contrib = (f32x4*)d_ws;                        // 50.3 MB
    half4* ftab    = (half4*)(contrib + total_nodes);     // 25.2 MB

    // Kernel 1: contrib + packed parent (4 nodes/thread)
    k_contrib<<<(int)(total_nodes / 4 / 256), 256, 0, stream>>>(
        attrs, residue, parent, W0, W1, W2, b0, b1, b2, contrib);

    // Kernel 2: geometric chunks with multi-chain ILP
    k_scan<2, true ><<< 4096 / 2 * BC / 256,   256, 0, stream>>>(contrib, ftab, 0,     4096);
    k_scan<4, false><<< 12288 / 4 * BC / 256,  256, 0, stream>>>(contrib, ftab, 4096,  12288);
    k_scan<4, false><<< 49152 / 4 * BC / 256,  256, 0, stream>>>(contrib, ftab, 16384, 49152);
    k_scan<8, false><<< 196608 / 8 * BC / 256, 256, 0, stream>>>(contrib, ftab, 65536, 196608);

    // Kernel 3: pixel gather (16 px/thread, nontemporal streams)
    k_gather<<<(int)((size_t)BC * HWPIX / 4096), 256, 0, stream>>>(
        ftab, pixel_node, out);
}

// Round 9
// 351.818 us; speedup vs baseline: 1.0988x; 1.0988x over previous
//
#include <hip/hip_runtime.h>

#define NNODES 262144          // N = 2^18
#define HWPIX  1048576         // H*W = 2^20
#define BC     12              // B*C

typedef _Float16 half4 __attribute__((ext_vector_type(4)));
typedef float    f32x4 __attribute__((ext_vector_type(4)));
typedef int      i32x4 __attribute__((ext_vector_type(4)));

__device__ __forceinline__ float sigm(float x) {
    return 1.0f / (1.0f + __expf(-x));
}

// bijective XCD swizzle (requires gridDim.x % 8 == 0, true for all our grids)
__device__ __forceinline__ int xcd_swizzle(int orig, int nwg) {
    int q = nwg >> 3;
    return (orig & 7) * q + (orig >> 3);
}

// Kernel 1: contrib_g = sigmoid(attrs . W_g + b_g) * residue, packed as
// f32x4 {c0,c1,c2,as_float(parent)} -> one 16B gather per chain hop.
// nt loads on read-once streams (validated R6: FETCH down, no write harm).
__global__ __launch_bounds__(256) void k_contrib(
    const float* __restrict__ attrs,   // (BC, N, 3)
    const float* __restrict__ residue, // (BC, N)
    const int*   __restrict__ parent,  // (BC, N)
    const float* __restrict__ W0, const float* __restrict__ W1,
    const float* __restrict__ W2, const float* __restrict__ b0,
    const float* __restrict__ b1, const float* __restrict__ b2,
    f32x4* __restrict__ contrib)       // (BC*N)
{
    const float w0 = W0[0], w10 = W1[0], w11 = W1[1], w2 = W2[0];
    const float c0 = b0[0], c1 = b1[0], c2 = b2[0];

    int t = blockIdx.x * blockDim.x + threadIdx.x;   // quad-node index
    const f32x4* a4 = (const f32x4*)attrs + (size_t)t * 3;
    f32x4 A  = __builtin_nontemporal_load(a4);
    f32x4 Bv = __builtin_nontemporal_load(a4 + 1);
    f32x4 Cv = __builtin_nontemporal_load(a4 + 2);
    f32x4 r  = __builtin_nontemporal_load((const f32x4*)residue + t);
    i32x4 par = __builtin_nontemporal_load((const i32x4*)parent + t);

    f32x4 o0, o1, o2, o3;
    o0.x = r.x * sigm(A.x * w0 + c0);
    o0.y = r.x * sigm(A.y * w10 + A.z * w11 + c1);
    o0.z = r.x * sigm(A.y * w2 + c2);
    o0.w = __int_as_float(par.x);
    o1.x = r.y * sigm(A.w * w0 + c0);
    o1.y = r.y * sigm(Bv.x * w10 + Bv.y * w11 + c1);
    o1.z = r.y * sigm(Bv.x * w2 + c2);
    o1.w = __int_as_float(par.y);
    o2.x = r.z * sigm(Bv.z * w0 + c0);
    o2.y = r.z * sigm(Bv.w * w10 + Cv.x * w11 + c1);
    o2.z = r.z * sigm(Bv.w * w2 + c2);
    o2.w = __int_as_float(par.z);
    o3.x = r.w * sigm(Cv.y * w0 + c0);
    o3.y = r.w * sigm(Cv.z * w10 + Cv.w * w11 + c1);
    o3.z = r.w * sigm(Cv.z * w2 + c2);
    o3.w = __int_as_float(par.w);

    f32x4* dst = contrib + (size_t)t * 4;
    dst[0] = o0; dst[1] = o1; dst[2] = o2; dst[3] = o3;
}

// Kernel 2 (x4 geometric chunks): f[i] = contrib[i] + f[parent-chain].
// CH independent chains per thread -> CH outstanding dependent gathers.
template<int CH, bool BASE>
__global__ __launch_bounds__(256) void k_scan(
    const f32x4* __restrict__ contrib,
    half4* __restrict__ ftab,          // fp16 x3 (+pad), 8B/node
    int lo, int cnt)                   // nodes [lo, lo+cnt) per tree
{
    int w = xcd_swizzle(blockIdx.x, gridDim.x);
    const int sub = cnt / CH;          // chains per k-slot per tree
    const int bpt = sub >> 8;          // blocks per tree
    int bc = w / bpt;
    int i0 = lo + (w % bpt) * 256 + threadIdx.x;
    const f32x4* C = contrib + ((size_t)bc << 18);
    half4* F = ftab + ((size_t)bc << 18);

    int   j[CH];
    float ax[CH], ay[CH], az[CH];
    #pragma unroll
    for (int k = 0; k < CH; ++k) {
        f32x4 e = C[i0 + k * sub];
        ax[k] = e.x; ay[k] = e.y; az[k] = e.z;
        j[k] = __float_as_int(e.w);
    }

    bool any = false;
    #pragma unroll
    for (int k = 0; k < CH; ++k)
        any |= BASE ? (j[k] != NNODES) : (j[k] >= lo);

    while (any) {
        f32x4 e[CH];
        #pragma unroll
        for (int k = 0; k < CH; ++k) {
            bool act = BASE ? (j[k] != NNODES) : (j[k] >= lo);
            e[k] = C[act ? j[k] : 0];   // inactive -> index 0, lanes merge to 1 req
        }
        any = false;
        #pragma unroll
        for (int k = 0; k < CH; ++k) {
            bool act = BASE ? (j[k] != NNODES) : (j[k] >= lo);
            if (act) {
                ax[k] += e[k].x; ay[k] += e[k].y; az[k] += e[k].z;
                j[k] = __float_as_int(e[k].w);
            }
            any |= BASE ? (j[k] != NNODES) : (j[k] >= lo);
        }
    }

    if (BASE) {
        #pragma unroll
        for (int k = 0; k < CH; ++k) {
            half4 h = {(_Float16)ax[k], (_Float16)ay[k], (_Float16)az[k], (_Float16)0.f};
            F[i0 + k * sub] = h;
        }
    } else {
        half4 fp[CH];
        #pragma unroll
        for (int k = 0; k < CH; ++k) fp[k] = F[j[k]];   // finalized ancestors
        #pragma unroll
        for (int k = 0; k < CH; ++k) {
            float fx = ax[k] + (float)fp[k].x;
            float fy = ay[k] + (float)fp[k].y;
            float fz = az[k] + (float)fp[k].z;
            half4 h = {(_Float16)fx, (_Float16)fy, (_Float16)fz, (_Float16)0.f};
            F[i0 + k * sub] = h;
        }
    }
}

// Kernel 3: pixel gather (R3 form — 8 px/thread, PLAIN loads/stores; nt
// stores caused 59% write amplification in R6). f-table fp16, ~3MB/XCD
// after swizzle -> L2-resident. Request-throughput-bound at ~1 gather/px.
__global__ __launch_bounds__(256) void k_gather(
    const half4* __restrict__ f,           // (BC*N)
    const int*   __restrict__ pixel_node,  // (BC, HW)
    float* __restrict__ out)               // (BC, 3, HW)
{
    int w = xcd_swizzle(blockIdx.x, gridDim.x);
    size_t gp = (size_t)w * 2048 + (size_t)threadIdx.x * 8;
    int bc = (int)(gp >> 20);              // HWPIX = 2^20
    int p  = (int)(gp & (HWPIX - 1));
    const i32x4* pn4 = (const i32x4*)(pixel_node + gp);
    i32x4 pa = pn4[0], pb = pn4[1];
    const half4* fb = f + ((size_t)bc << 18);
    half4 f0 = fb[pa.x], f1 = fb[pa.y], f2 = fb[pa.z], f3 = fb[pa.w];
    half4 f4 = fb[pb.x], f5 = fb[pb.y], f6 = fb[pb.z], f7 = fb[pb.w];
    float* o = out + (size_t)bc * 3 * HWPIX + p;

    f32x4 s0 = {f0.x, f1.x, f2.x, f3.x};
    f32x4 s1 = {f4.x, f5.x, f6.x, f7.x};
    *(f32x4*)(o)     = s0;
    *(f32x4*)(o + 4) = s1;

    f32x4 t0 = {f0.y, f1.y, f2.y, f3.y};
    f32x4 t1 = {f4.y, f5.y, f6.y, f7.y};
    *(f32x4*)(o + HWPIX)     = t0;
    *(f32x4*)(o + HWPIX + 4) = t1;

    f32x4 u0 = {f0.z, f1.z, f2.z, f3.z};
    f32x4 u1 = {f4.z, f5.z, f6.z, f7.z};
    *(f32x4*)(o + 2 * HWPIX)     = u0;
    *(f32x4*)(o + 2 * HWPIX + 4) = u1;
}

extern "C" void kernel_launch(void* const* d_in, const int* in_sizes, int n_in,
                              void* d_out, int out_size, void* d_ws, size_t ws_size,
                              hipStream_t stream) {
    const float* attrs      = (const float*)d_in[0];
    const float* residue    = (const float*)d_in[1];
    const float* W0         = (const float*)d_in[2];
    const float* W1         = (const float*)d_in[3];
    const float* W2         = (const float*)d_in[4];
    const float* b0         = (const float*)d_in[5];
    const float* b1         = (const float*)d_in[6];
    const float* b2         = (const float*)d_in[7];
    const int*   parent     = (const int*)d_in[8];
    const int*   pixel_node = (const int*)d_in[9];
    float* out = (float*)d_out;

    const size_t total_nodes = (size_t)BC * NNODES;       // 3,145,728
    f32x4* contrib = (f32x4*)d_ws;                        // 50.3 MB
    half4* ftab    = (half4*)(contrib + total_nodes);     // 25.2 MB

    // Kernel 1: contrib + packed parent (4 nodes/thread)
    k_contrib<<<(int)(total_nodes / 4 / 256), 256, 0, stream>>>(
        attrs, residue, parent, W0, W1, W2, b0, b1, b2, contrib);

    // Kernel 2: geometric chunks with multi-chain ILP
    k_scan<2, true ><<< 4096 / 2 * BC / 256,   256, 0, stream>>>(contrib, ftab, 0,     4096);
    k_scan<4, false><<< 12288 / 4 * BC / 256,  256, 0, stream>>>(contrib, ftab, 4096,  12288);
    k_scan<4, false><<< 49152 / 4 * BC / 256,  256, 0, stream>>>(contrib, ftab, 16384, 49152);
    k_scan<8, false><<< 196608 / 8 * BC / 256, 256, 0, stream>>>(contrib, ftab, 65536, 196608);

    // Kernel 3: pixel gather (8 px/thread, plain streams)
    k_gather<<<(int)((size_t)BC * HWPIX / 2048), 256, 0, stream>>>(
        ftab, pixel_node, out);
}